// Round 1
// baseline (223.990 us; speedup 1.0000x reference)
//
#include <hip/hip_runtime.h>

// Problem constants
#define NROWS 65536   // 64*64*32*32 / 64
#define KC    1024
#define DD    64

// Output layout (floats) in d_out
#define QOFF  0                     // quantized_st: 4194304
#define IOFF  4194304               // indices:        65536
#define WOFF  4259840               // new_weight:     65536
#define CSOFF 4325376               // cs:              1024
#define EAOFF 4326400               // new_embed_avg:  65536

// Workspace layout (floats)
#define WS_CODESQ 0        // 1024
#define WS_COUNTS 1024     // 1024
#define WS_DW     2048     // 65536
#define WS_CSFIN  67584    // 1024

__device__ __forceinline__ float rowsq_np(const float* __restrict__ x) {
    // Replicates numpy pairwise_sum for n=64 over m[i] = fl(x[i]*x[i]):
    // r[j] = m[j] + m[8+j] + ... + m[56+j] (sequential), then
    // ((r0+r1)+(r2+r3)) + ((r4+r5)+(r6+r7)). No FMA contraction allowed.
    float r[8];
#pragma unroll
    for (int j = 0; j < 8; ++j) r[j] = __fmul_rn(x[j], x[j]);
#pragma unroll
    for (int i = 8; i < 64; i += 8) {
#pragma unroll
        for (int j = 0; j < 8; ++j)
            r[j] = __fadd_rn(r[j], __fmul_rn(x[i + j], x[i + j]));
    }
    float s01 = __fadd_rn(r[0], r[1]);
    float s23 = __fadd_rn(r[2], r[3]);
    float s45 = __fadd_rn(r[4], r[5]);
    float s67 = __fadd_rn(r[6], r[7]);
    return __fadd_rn(__fadd_rn(s01, s23), __fadd_rn(s45, s67));
}

// ---- Kernel A: code_sq[k] = sum_d w[k][d]^2 (numpy pairwise order) ----
__global__ void code_sq_kernel(const float* __restrict__ weight,
                               float* __restrict__ code_sq) {
    int c = blockIdx.x * blockDim.x + threadIdx.x;
    if (c >= KC) return;
    float wv[64];
    const float4* pw = reinterpret_cast<const float4*>(weight + (size_t)c * DD);
#pragma unroll
    for (int i = 0; i < 16; ++i) {
        float4 v = pw[i];
        wv[4 * i] = v.x; wv[4 * i + 1] = v.y; wv[4 * i + 2] = v.z; wv[4 * i + 3] = v.w;
    }
    code_sq[c] = rowsq_np(wv);
}

// ---- Kernel B: distances + argmin + quantized + indices + counts + dw ----
// 512 blocks x 256 threads (4 waves). Block handles 128 rows.
// Thread (any wave) lane l owns rows 2l, 2l+1 (x kept in VGPRs).
// Wave s scans codes {tile*128 + s*32 + kk} -> LDS broadcast reads.
__global__ __launch_bounds__(256, 2) void vq_main(
    const float* __restrict__ x_in, const float* __restrict__ weight,
    const float* __restrict__ code_sq, float* __restrict__ out,
    float* __restrict__ counts, float* __restrict__ dw) {

    __shared__ float lds_w[128 * 64];     // 32 KB weight tile
    __shared__ float lds_csq[128];
    __shared__ float s_best[4 * 128];
    __shared__ int   s_bidx[4 * 128];
    __shared__ int   idx_lds[128];

    const int tid  = threadIdx.x;
    const int lane = tid & 63;
    const int wv   = tid >> 6;            // wave id 0..3 = K-split

    const size_t row0 = (size_t)blockIdx.x * 128 + 2 * lane;

    // Load 2 rows of x into registers (128 floats)
    float x0[64], x1[64];
    const float4* px = reinterpret_cast<const float4*>(x_in + row0 * DD);
#pragma unroll
    for (int i = 0; i < 16; ++i) {
        float4 v = px[i];
        x0[4 * i] = v.x; x0[4 * i + 1] = v.y; x0[4 * i + 2] = v.z; x0[4 * i + 3] = v.w;
    }
#pragma unroll
    for (int i = 0; i < 16; ++i) {
        float4 v = px[16 + i];
        x1[4 * i] = v.x; x1[4 * i + 1] = v.y; x1[4 * i + 2] = v.z; x1[4 * i + 3] = v.w;
    }

    const float rs0 = rowsq_np(x0);
    const float rs1 = rowsq_np(x1);

    float best0 = INFINITY, best1 = INFINITY;
    int bidx0 = 0, bidx1 = 0;

    for (int t = 0; t < KC / 128; ++t) {
        __syncthreads();
        // Stage 128-code weight tile (8192 floats) + its code_sq
        const float4* wsrc = reinterpret_cast<const float4*>(weight + (size_t)t * 128 * DD);
        float4* ldst = reinterpret_cast<float4*>(lds_w);
#pragma unroll
        for (int j = 0; j < 8; ++j) ldst[tid + j * 256] = wsrc[tid + j * 256];
        if (tid < 128) lds_csq[tid] = code_sq[t * 128 + tid];
        __syncthreads();

#pragma unroll 2
        for (int kk = 0; kk < 32; ++kk) {
            const int kl = wv * 32 + kk;
            const float* wrow = lds_w + kl * 64;
            float a00 = 0.f, a01 = 0.f, a02 = 0.f, a03 = 0.f;
            float a10 = 0.f, a11 = 0.f, a12 = 0.f, a13 = 0.f;
#pragma unroll
            for (int d = 0; d < 64; d += 4) {
                float4 w4 = *reinterpret_cast<const float4*>(wrow + d); // broadcast
                a00 += x0[d]     * w4.x;  a01 += x0[d + 1] * w4.y;
                a02 += x0[d + 2] * w4.z;  a03 += x0[d + 3] * w4.w;
                a10 += x1[d]     * w4.x;  a11 += x1[d + 1] * w4.y;
                a12 += x1[d + 2] * w4.z;  a13 += x1[d + 3] * w4.w;
            }
            float dot0 = (a00 + a01) + (a02 + a03);
            float dot1 = (a10 + a11) + (a12 + a13);
            float csq  = lds_csq[kl];
            // dist = fl(fl(rs + csq) - 2*dot)  (2*dot is exact)
            float d0 = __fsub_rn(__fadd_rn(rs0, csq), __fmul_rn(2.0f, dot0));
            float d1 = __fsub_rn(__fadd_rn(rs1, csq), __fmul_rn(2.0f, dot1));
            int kg = t * 128 + kl;
            if (d0 < best0) { best0 = d0; bidx0 = kg; }
            if (d1 < best1) { best1 = d1; bidx1 = kg; }
        }
    }

    // Publish per-wave candidates
    s_best[wv * 128 + 2 * lane]     = best0;
    s_best[wv * 128 + 2 * lane + 1] = best1;
    s_bidx[wv * 128 + 2 * lane]     = bidx0;
    s_bidx[wv * 128 + 2 * lane + 1] = bidx1;
    __syncthreads();

    // Wave 0 combines (lexicographic: min value, then min index)
    if (wv == 0) {
#pragma unroll
        for (int rr = 0; rr < 2; ++rr) {
            int rl = 2 * lane + rr;
            float bvv = s_best[rl];
            int   bii = s_bidx[rl];
#pragma unroll
            for (int s = 1; s < 4; ++s) {
                float v = s_best[s * 128 + rl];
                int   i = s_bidx[s * 128 + rl];
                if (v < bvv || (v == bvv && i < bii)) { bvv = v; bii = i; }
            }
            size_t grow = (size_t)blockIdx.x * 128 + rl;
            out[IOFF + grow] = (float)bii;
            atomicAdd(&counts[bii], 1.0f);
            idx_lds[rl] = bii;
        }
    }
    __syncthreads();

    // Epilogue: quantized_st + dw atomics. Block region = 128 rows * 64 d
    // = 2048 float4. Coalesced re-read of x from global (L2-hot).
    const size_t blk_f4 = (size_t)blockIdx.x * 2048;
    const float4* xin4 = reinterpret_cast<const float4*>(x_in);
    float4* q4 = reinterpret_cast<float4*>(out + QOFF);
#pragma unroll
    for (int j = 0; j < 8; ++j) {
        int f4i = tid + j * 256;
        int fpos = f4i * 4;
        int rl = fpos >> 6;
        int d0 = fpos & 63;
        int idx = idx_lds[rl];
        float4 xv = xin4[blk_f4 + f4i];
        float4 wvv = *reinterpret_cast<const float4*>(weight + (size_t)idx * DD + d0);
        float4 qv;
        qv.x = __fadd_rn(xv.x, __fsub_rn(wvv.x, xv.x));
        qv.y = __fadd_rn(xv.y, __fsub_rn(wvv.y, xv.y));
        qv.z = __fadd_rn(xv.z, __fsub_rn(wvv.z, xv.z));
        qv.w = __fadd_rn(xv.w, __fsub_rn(wvv.w, xv.w));
        q4[blk_f4 + f4i] = qv;
        float* dwp = dw + (size_t)idx * DD + d0;
        atomicAdd(dwp + 0, xv.x);
        atomicAdd(dwp + 1, xv.y);
        atomicAdd(dwp + 2, xv.z);
        atomicAdd(dwp + 3, xv.w);
    }
}

// ---- Kernel C: cs update + normalize (needs n = sum cs) ----
__global__ void finalize_cs(const float* __restrict__ cluster_size,
                            const float* __restrict__ counts,
                            float* __restrict__ out,
                            float* __restrict__ cs_fin) {
    __shared__ float sb[1024];
    int k = threadIdx.x;
    float c = 0.99f * cluster_size[k] + 0.01f * counts[k];
    sb[k] = c;
    __syncthreads();
    for (int off = 512; off > 0; off >>= 1) {
        if (k < off) sb[k] += sb[k + off];
        __syncthreads();
    }
    float n = sb[0];
    float v = ((c + 1e-5f) / (n + 0.01024f)) * n;
    out[CSOFF + k] = v;
    cs_fin[k] = v;
}

// ---- Kernel D: EMA embed_avg + new weights ----
__global__ void finalize_w(const float* __restrict__ embed_avg,
                           const float* __restrict__ dw,
                           const float* __restrict__ cs_fin,
                           float* __restrict__ out) {
    int e = blockIdx.x * blockDim.x + threadIdx.x;
    if (e >= KC * DD) return;
    float na = 0.99f * embed_avg[e] + 0.01f * dw[e];
    float nw = na / cs_fin[e >> 6];
    out[EAOFF + e] = na;
    out[WOFF + e] = nw;
}

extern "C" void kernel_launch(void* const* d_in, const int* in_sizes, int n_in,
                              void* d_out, int out_size, void* d_ws, size_t ws_size,
                              hipStream_t stream) {
    (void)in_sizes; (void)n_in; (void)out_size; (void)ws_size;
    const float* x       = (const float*)d_in[0];
    const float* weight  = (const float*)d_in[1];
    const float* cluster = (const float*)d_in[2];
    const float* eavg    = (const float*)d_in[3];
    float* out = (float*)d_out;
    float* wsf = (float*)d_ws;

    float* code_sq = wsf + WS_CODESQ;
    float* counts  = wsf + WS_COUNTS;
    float* dwbuf   = wsf + WS_DW;
    float* cs_fin  = wsf + WS_CSFIN;

    // zero counts + dw (contiguous region)
    hipMemsetAsync(counts, 0, (size_t)(1024 + 65536) * sizeof(float), stream);

    hipLaunchKernelGGL(code_sq_kernel, dim3(4), dim3(256), 0, stream, weight, code_sq);
    hipLaunchKernelGGL(vq_main, dim3(512), dim3(256), 0, stream,
                       x, weight, code_sq, out, counts, dwbuf);
    hipLaunchKernelGGL(finalize_cs, dim3(1), dim3(1024), 0, stream,
                       cluster, counts, out, cs_fin);
    hipLaunchKernelGGL(finalize_w, dim3(256), dim3(256), 0, stream,
                       eavg, dwbuf, cs_fin, out);
}